// Round 1
// baseline (144.937 us; speedup 1.0000x reference)
//
#include <hip/hip_runtime.h>
#include <math.h>

// MatchAttention fused forward, fp32.
// B=2, H=W=64 (N=4096), C=256, h=8 heads (Ch=32), r=3 -> 7x7=49 window.
constexpr int B = 2, H = 64, W = 64, C = 256, NH = 8, CH = 32;
constexpr int R = 3, KW = 7, KK = 49, N = H * W;
constexpr int QCH = 8;  // channels per thread (quarter of a head)

// One block = one (b, g, row): 64 pixels x 4 channel-quarters = 256 threads.
// The 4 quarter-lanes of a pixel together read exactly one 128B line per
// gather (position head-slice is 128B aligned in [B,N,C]) -> coalesced.
__global__ void __launch_bounds__(256) match_attn_kernel(
    const float* __restrict__ moff, const float* __restrict__ qp,
    const float* __restrict__ kp, const float* __restrict__ vp,
    float* __restrict__ outp, float* __restrict__ attnp) {
  const int t = threadIdx.x;
  const int quarter = t & 3;   // which 8-channel slice of the head
  const int xpix = t >> 2;     // 0..63 pixel within row
  int bb = blockIdx.x;
  const int y = bb % H; bb /= H;
  const int g = bb % NH;
  const int b = bb / NH;
  const int n = y * W + xpix;

  // per-pixel, per-head rounded (dy,dx) offset; rintf == round-half-to-even
  const float2 off = *(const float2*)(moff + ((size_t)(b * N + n) * NH + g) * 2);
  const int cy = y + (int)rintf(off.x);
  const int cx = xpix + (int)rintf(off.y);

  const float* qbase = qp + (size_t)(b * N + n) * C + g * CH + quarter * QCH;
  const float4 q0 = *(const float4*)(qbase);
  const float4 q1 = *(const float4*)(qbase + 4);

  const float* kb = kp + (size_t)b * N * C + g * CH + quarter * QCH;
  const float* vb = vp + (size_t)b * N * C + g * CH + quarter * QCH;

  float sim[KK];
  float mx = -1e30f;
#pragma unroll
  for (int kk = 0; kk < KK; ++kk) {
    const int dy = kk / KW - R, dx = kk % KW - R;
    int py = cy + dy; py = min(max(py, 0), H - 1);
    int px = cx + dx; px = min(max(px, 0), W - 1);
    const int idx = py * W + px;
    const float* kr = kb + (size_t)idx * C;
    const float4 k0 = *(const float4*)(kr);
    const float4 k1 = *(const float4*)(kr + 4);
    float s = fabsf(q0.x - k0.x) + fabsf(q0.y - k0.y) +
              fabsf(q0.z - k0.z) + fabsf(q0.w - k0.w) +
              fabsf(q1.x - k1.x) + fabsf(q1.y - k1.y) +
              fabsf(q1.z - k1.z) + fabsf(q1.w - k1.w);
    // combine the 4 quarter-partials (lanes xor 1, xor 2 are same pixel)
    s += __shfl_xor(s, 1);
    s += __shfl_xor(s, 2);
    s = -s;                    // sim = -scale * L1, scale = 1
    sim[kk] = s;
    mx = fmaxf(mx, s);
  }

  float denom = 0.f;
#pragma unroll
  for (int kk = 0; kk < KK; ++kk) {
    const float e = __expf(sim[kk] - mx);
    denom += e;
    sim[kk] = e;
  }
  const float inv = 1.0f / denom;

  float* attn_px = attnp + ((size_t)(b * N + n) * NH + g) * KK;
  float4 a0 = {0.f, 0.f, 0.f, 0.f}, a1 = {0.f, 0.f, 0.f, 0.f};
#pragma unroll
  for (int kk = 0; kk < KK; ++kk) {
    const float w = sim[kk] * inv;
    if ((kk & 3) == quarter) attn_px[kk] = w;  // each attn elem written once
    const int dy = kk / KW - R, dx = kk % KW - R;
    int py = cy + dy; py = min(max(py, 0), H - 1);
    int px = cx + dx; px = min(max(px, 0), W - 1);
    const int idx = py * W + px;
    const float* vr = vb + (size_t)idx * C;
    const float4 v0 = *(const float4*)(vr);
    const float4 v1 = *(const float4*)(vr + 4);
    a0.x += w * v0.x; a0.y += w * v0.y; a0.z += w * v0.z; a0.w += w * v0.w;
    a1.x += w * v1.x; a1.y += w * v1.y; a1.z += w * v1.z; a1.w += w * v1.w;
  }

  float* ob = outp + (size_t)(b * N + n) * C + g * CH + quarter * QCH;
  *(float4*)ob = a0;
  *(float4*)(ob + 4) = a1;
}

extern "C" void kernel_launch(void* const* d_in, const int* in_sizes, int n_in,
                              void* d_out, int out_size, void* d_ws, size_t ws_size,
                              hipStream_t stream) {
  const float* moff = (const float*)d_in[0];  // [B,N,h,2]
  const float* q    = (const float*)d_in[1];  // [B,N,C]
  const float* k    = (const float*)d_in[2];  // [B,N,C]
  const float* v    = (const float*)d_in[3];  // [B,N,C]
  // d_in[4..7] = H, W, r_h, r_w scalars; fixed for this problem (64,64,3,3).
  float* out  = (float*)d_out;                       // [B,N,C]
  float* attn = out + (size_t)B * N * C;             // [B,N,h,K]

  const int grid = B * NH * H;  // 1024 blocks of 256 threads
  match_attn_kernel<<<grid, 256, 0, stream>>>(moff, q, k, v, out, attn);
}